// Round 2
// baseline (6278.846 us; speedup 1.0000x reference)
//
#include <hip/hip_runtime.h>
#include <math.h>

// Problem constants (fixed by the reference)
#define NPTS 500000
#define SCALE 0.35355339059327373f   // 1/sqrt(8)
#define NTILES 7813                  // ceil(500000/64)
#define TPB 4                        // tiles per block
#define GRID ((NTILES + TPB - 1) / TPB)
#define Q4TOT 8000000                // NPTS*16 float4's in q / e / out

// ws layout (float offsets):
// [0,4096)      WqT[k][c] = Wq[c][k]
// [4096,8192)   WoT[c][c'] = Wo[c'][c]
// [8192,8704)   khs[b][c] = (k@Wk.T + bk)*scale
// [8704,9216)   vh[b][c]  = v@Wv.T + bv
// [9216,10240)  z as double[512]

// W column fragment loader: w_j = W[4j..4j+3][c]  (coalesced: lanes are consecutive c)
__device__ __forceinline__ float4 ldw4(const float* __restrict__ WB, int j, int c) {
    return make_float4(WB[(4 * j + 0) * 64 + c], WB[(4 * j + 1) * 64 + c],
                       WB[(4 * j + 2) * 64 + c], WB[(4 * j + 3) * 64 + c]);
}

#define DECLW float4 w0, w1, w2, w3, w4, w5, w6, w7, w8, w9, w10, w11, w12, w13, w14, w15
#define LOADW(WB) do { \
    w0  = ldw4((WB), 0, c);  w1  = ldw4((WB), 1, c);  w2  = ldw4((WB), 2, c);  w3  = ldw4((WB), 3, c);  \
    w4  = ldw4((WB), 4, c);  w5  = ldw4((WB), 5, c);  w6  = ldw4((WB), 6, c);  w7  = ldw4((WB), 7, c);  \
    w8  = ldw4((WB), 8, c);  w9  = ldw4((WB), 9, c);  w10 = ldw4((WB), 10, c); w11 = ldw4((WB), 11, c); \
    w12 = ldw4((WB), 12, c); w13 = ldw4((WB), 13, c); w14 = ldw4((WB), 14, c); w15 = ldw4((WB), 15, c); \
} while (0)

// One K-chunk (4 k-values) for 4 points. All LDS reads are 64-lane-uniform broadcasts.
#define STEP(J, WJ) do { \
    aa = ra[J]; ab = rb[J]; ac = rc[J]; ad = rd[J]; \
    sa = fmaf(aa.x, WJ.x, sa); sb = fmaf(ab.x, WJ.x, sb); \
    sc = fmaf(ac.x, WJ.x, sc); sd = fmaf(ad.x, WJ.x, sd); \
    sa = fmaf(aa.y, WJ.y, sa); sb = fmaf(ab.y, WJ.y, sb); \
    sc = fmaf(ac.y, WJ.y, sc); sd = fmaf(ad.y, WJ.y, sd); \
    sa = fmaf(aa.z, WJ.z, sa); sb = fmaf(ab.z, WJ.z, sb); \
    sc = fmaf(ac.z, WJ.z, sc); sd = fmaf(ad.z, WJ.z, sd); \
    sa = fmaf(aa.w, WJ.w, sa); sb = fmaf(ab.w, WJ.w, sb); \
    sc = fmaf(ac.w, WJ.w, sc); sd = fmaf(ad.w, WJ.w, sd); \
} while (0)

// Full-K dot products for 4 consecutive tile rows P0..P0+3, channel c.
#define DOQUAD(TILE, P0, SA, SB, SC, SD) do { \
    const float4* ra = (const float4*)((TILE) + (P0) * 64); \
    const float4* rb = ra + 16; \
    const float4* rc = ra + 32; \
    const float4* rd = ra + 48; \
    float4 aa, ab, ac, ad; \
    float sa = 0.f, sb = 0.f, sc = 0.f, sd = 0.f; \
    STEP(0, w0);   STEP(1, w1);   STEP(2, w2);   STEP(3, w3);  \
    STEP(4, w4);   STEP(5, w5);   STEP(6, w6);   STEP(7, w7);  \
    STEP(8, w8);   STEP(9, w9);   STEP(10, w10); STEP(11, w11); \
    STEP(12, w12); STEP(13, w13); STEP(14, w14); STEP(15, w15); \
    SA = sa; SB = sb; SC = sc; SD = sd; \
} while (0)

__global__ void prep_kernel(const float* __restrict__ kin, const float* __restrict__ vin,
                            const float* __restrict__ Wq, const float* __restrict__ Wk,
                            const float* __restrict__ bk, const float* __restrict__ Wv,
                            const float* __restrict__ bv, const float* __restrict__ Wo,
                            float* __restrict__ ws) {
    const int gid = blockIdx.x * 256 + threadIdx.x;
    float* WqT = ws;
    float* WoT = ws + 4096;
    float* khs = ws + 8192;
    float* vh  = ws + 8704;
    double* zg = (double*)(ws + 9216);
    for (int idx = gid; idx < 4096; idx += 8 * 256) {
        int a = idx >> 6, b = idx & 63;
        WqT[idx] = Wq[b * 64 + a];
        WoT[idx] = Wo[b * 64 + a];
    }
    for (int idx = gid; idx < 512; idx += 8 * 256) {
        int b = idx >> 6, c = idx & 63;
        float dk = 0.f, dv = 0.f;
        #pragma unroll 8
        for (int j = 0; j < 64; ++j) {
            dk = fmaf(kin[b * 64 + j], Wk[c * 64 + j], dk);
            dv = fmaf(vin[b * 64 + j], Wv[c * 64 + j], dv);
        }
        khs[idx] = (dk + bk[c]) * SCALE;
        vh[idx]  = dv + bv[c];
        zg[idx]  = 0.0;
    }
}

// passA: e = exp((q@Wq.T + bq) * khs[batch]) -> e_out (aliases d_out), z-accum (f64 global)
// Thread = (channel c, point-group wid). W column in 16 NAMED float4 regs; q tile staged
// linearly; all compute-phase LDS reads are wave-uniform broadcasts.
__global__ __launch_bounds__(256, 2) void passA_kernel(const float* __restrict__ q,
                                                       const int* __restrict__ batch,
                                                       const float* __restrict__ bq,
                                                       float* __restrict__ ws,
                                                       float* __restrict__ e_out) {
    __shared__ __align__(16) float qtile[4096];   // [64 pts][64 k], linear
    __shared__ __align__(16) float khs_l[512];
    __shared__ __align__(16) float zred[256];

    const float* WqT   = ws;
    const float* khs_g = ws + 8192;
    double* zg = (double*)(ws + 9216);

    const int tid = threadIdx.x;
    const int wid = tid >> 6;     // point-group: rows 16*wid..16*wid+15
    const int c   = tid & 63;     // output channel

    for (int idx = tid; idx < 128; idx += 256)
        ((float4*)khs_l)[idx] = ((const float4*)khs_g)[idx];

    DECLW;
    LOADW(WqT);
    const float bqc = bq[c];

    float zacc = 0.f;
    int cur_b = -1;

    // block-uniform call sites only
    auto flushz = [&](int b) {
        if (b < 0) return;
        __syncthreads();               // zred reuse guard
        zred[tid] = zacc;
        __syncthreads();
        if (tid < 64) {
            float s = zred[tid] + zred[64 + tid] + zred[128 + tid] + zred[192 + tid];
            unsafeAtomicAdd(&zg[b * 64 + tid], (double)s);
        }
        zacc = 0.f;
    };

    const int t0 = blockIdx.x * TPB;
    const int t1 = (t0 + TPB < NTILES) ? (t0 + TPB) : NTILES;

    for (int t = t0; t < t1; ++t) {
        const int p0g = t * 64;

        // linear stage of the q tile (pure memcpy, zero-fill past NPTS)
        #pragma unroll
        for (int i = 0; i < 4; ++i) {
            const int g4 = t * 1024 + i * 256 + tid;
            float4 v = make_float4(0.f, 0.f, 0.f, 0.f);
            if (g4 < Q4TOT) v = ((const float4*)q)[g4];
            ((float4*)qtile)[i * 256 + tid] = v;
        }
        const int b_lo = batch[p0g];
        const int b_hi = batch[(p0g + 63 < NPTS) ? (p0g + 63) : (NPTS - 1)];
        const bool uni = (b_lo == b_hi);
        __syncthreads();

        if (uni) {
            if (cur_b != b_lo) { flushz(cur_b); cur_b = b_lo; }
        } else {
            flushz(cur_b);
            cur_b = -1;
        }

        float s00, s01, s02, s03, s04, s05, s06, s07;
        float s08, s09, s10, s11, s12, s13, s14, s15;
        DOQUAD(qtile, wid * 16 + 0,  s00, s01, s02, s03);
        DOQUAD(qtile, wid * 16 + 4,  s04, s05, s06, s07);
        DOQUAD(qtile, wid * 16 + 8,  s08, s09, s10, s11);
        DOQUAD(qtile, wid * 16 + 12, s12, s13, s14, s15);

        const int pbase = p0g + wid * 16;
        if (uni) {
            const float khb = khs_l[b_lo * 64 + c];
            #define EPIU(S, P) do { \
                const int gp = pbase + (P); \
                if (gp < NPTS) { \
                    const float e = __expf(((S) + bqc) * khb); \
                    e_out[gp * 64 + c] = e; \
                    zacc += e; \
                } \
            } while (0)
            EPIU(s00, 0);  EPIU(s01, 1);  EPIU(s02, 2);  EPIU(s03, 3);
            EPIU(s04, 4);  EPIU(s05, 5);  EPIU(s06, 6);  EPIU(s07, 7);
            EPIU(s08, 8);  EPIU(s09, 9);  EPIU(s10, 10); EPIU(s11, 11);
            EPIU(s12, 12); EPIU(s13, 13); EPIU(s14, 14); EPIU(s15, 15);
        } else {
            // rare boundary tile (<=7 in the whole grid)
            #define EPIB(S, P) do { \
                const int gp = pbase + (P); \
                if (gp < NPTS) { \
                    const int bi = batch[gp]; \
                    const float e = __expf(((S) + bqc) * khs_l[bi * 64 + c]); \
                    e_out[gp * 64 + c] = e; \
                    unsafeAtomicAdd(&zg[bi * 64 + c], (double)e); \
                } \
            } while (0)
            EPIB(s00, 0);  EPIB(s01, 1);  EPIB(s02, 2);  EPIB(s03, 3);
            EPIB(s04, 4);  EPIB(s05, 5);  EPIB(s06, 6);  EPIB(s07, 7);
            EPIB(s08, 8);  EPIB(s09, 9);  EPIB(s10, 10); EPIB(s11, 11);
            EPIB(s12, 12); EPIB(s13, 13); EPIB(s14, 14); EPIB(s15, 15);
        }
        __syncthreads();   // qtile about to be restaged
    }
    flushz(cur_b);
}

// passB: out = (e * (vh/z)[batch]) @ Wo.T + bo ; e read from d_out, written in place.
// vh/z is folded into the A side at stage time, so the W registers are constant for the
// whole kernel and boundary tiles need no special compute path.
__global__ __launch_bounds__(256, 2) void passB_kernel(const int* __restrict__ batch,
                                                       const float* __restrict__ bo,
                                                       const float* __restrict__ ws,
                                                       float* __restrict__ out) {
    __shared__ __align__(16) float ttile[4096];
    __shared__ __align__(16) float w_l[512];

    const float* WoT  = ws + 4096;
    const float* vh_g = ws + 8704;
    const double* zg  = (const double*)(ws + 9216);

    const int tid = threadIdx.x;
    const int wid = tid >> 6;
    const int c   = tid & 63;
    const int c16 = tid & 15;

    for (int idx = tid; idx < 512; idx += 256)
        w_l[idx] = (float)((double)vh_g[idx] / zg[idx]);

    DECLW;
    LOADW(WoT);
    const float boc = bo[c];

    const int t0 = blockIdx.x * TPB;
    const int t1 = (t0 + TPB < NTILES) ? (t0 + TPB) : NTILES;
    __syncthreads();   // w_l ready

    for (int t = t0; t < t1; ++t) {
        const int p0g = t * 64;
        const int b_lo = batch[p0g];
        const int b_hi = batch[(p0g + 63 < NPTS) ? (p0g + 63) : (NPTS - 1)];
        const bool uni = (b_lo == b_hi);

        // stage t = e * w[batch], linear layout, fold applied elementwise
        #pragma unroll
        for (int i = 0; i < 4; ++i) {
            const int g4 = t * 1024 + i * 256 + tid;
            float4 v = make_float4(0.f, 0.f, 0.f, 0.f);
            if (g4 < Q4TOT) v = ((const float4*)out)[g4];
            int bi = b_lo;
            if (!uni) {
                const int gp = p0g + ((i * 256 + tid) >> 4);
                bi = batch[(gp < NPTS) ? gp : (NPTS - 1)];
            }
            const float4 wv = *(const float4*)&w_l[bi * 64 + c16 * 4];
            v.x *= wv.x; v.y *= wv.y; v.z *= wv.z; v.w *= wv.w;
            ((float4*)ttile)[i * 256 + tid] = v;
        }
        __syncthreads();

        float s00, s01, s02, s03, s04, s05, s06, s07;
        float s08, s09, s10, s11, s12, s13, s14, s15;
        DOQUAD(ttile, wid * 16 + 0,  s00, s01, s02, s03);
        DOQUAD(ttile, wid * 16 + 4,  s04, s05, s06, s07);
        DOQUAD(ttile, wid * 16 + 8,  s08, s09, s10, s11);
        DOQUAD(ttile, wid * 16 + 12, s12, s13, s14, s15);

        const int pbase = p0g + wid * 16;
        #define OUTP(S, P) do { \
            const int gp = pbase + (P); \
            if (gp < NPTS) out[gp * 64 + c] = (S) + boc; \
        } while (0)
        OUTP(s00, 0);  OUTP(s01, 1);  OUTP(s02, 2);  OUTP(s03, 3);
        OUTP(s04, 4);  OUTP(s05, 5);  OUTP(s06, 6);  OUTP(s07, 7);
        OUTP(s08, 8);  OUTP(s09, 9);  OUTP(s10, 10); OUTP(s11, 11);
        OUTP(s12, 12); OUTP(s13, 13); OUTP(s14, 14); OUTP(s15, 15);
        __syncthreads();   // ttile about to be restaged
    }
}

extern "C" void kernel_launch(void* const* d_in, const int* in_sizes, int n_in,
                              void* d_out, int out_size, void* d_ws, size_t ws_size,
                              hipStream_t stream) {
    const float* q   = (const float*)d_in[0];
    const float* k   = (const float*)d_in[1];
    const float* v   = (const float*)d_in[2];
    const float* Wq  = (const float*)d_in[3];
    const float* bq  = (const float*)d_in[4];
    const float* Wk  = (const float*)d_in[5];
    const float* bk  = (const float*)d_in[6];
    const float* Wv  = (const float*)d_in[7];
    const float* bv  = (const float*)d_in[8];
    const float* Wo  = (const float*)d_in[9];
    const float* bo  = (const float*)d_in[10];
    const int*  batch = (const int*)d_in[11];
    float* out = (float*)d_out;
    float* ws  = (float*)d_ws;

    prep_kernel<<<8, 256, 0, stream>>>(k, v, Wq, Wk, bk, Wv, bv, Wo, ws);
    passA_kernel<<<GRID, 256, 0, stream>>>(q, batch, bq, ws, out);
    passB_kernel<<<GRID, 256, 0, stream>>>(batch, bo, ws, out);
}

// Round 3
// 349.562 us; speedup vs baseline: 17.9620x; 17.9620x over previous
//
#include <hip/hip_runtime.h>
#include <math.h>

// Problem constants (fixed by the reference)
#define NPTS 500000
#define SCALE 0.35355339059327373f   // 1/sqrt(8)
#define NT128 3907                   // ceil(500000/128)
#define TPB 2                        // 128-pt tiles per block
#define GRID ((NT128 + TPB - 1) / TPB)
#define Q4TOT 8000000                // NPTS*16 float4's in q / e / out

// Transposed 128-pt tile layout: element (k,p) lives at
//   (k>>2)*532 + (k&3)*132 + p
// Group stride 532 == 20 (mod 32): staging scalar writes from 16 k-chunks x 4 pts
// cover all 32 banks 2-way (free, m136). Rows are 132 floats (528 B, 16B-aligned)
// so float4 reads at p=4*ty are aligned and hit 8 distinct bank-quads.
#define QTIDX(k, p) ((((k) >> 2) * 532) + (((k) & 3) * 132) + (p))
#define QT_SZ 8512

// ws layout (float offsets):
// [0,4096)      WqT[k][c] = Wq[c][k]
// [4096,8192)   WoT[c][c'] = Wo[c'][c]
// [8192,8704)   khs[b][c] = (k@Wk.T + bk)*scale
// [8704,9216)   vh[b][c]  = v@Wv.T + bv
// [9216,10240)  z as double[512]

__global__ void prep_kernel(const float* __restrict__ kin, const float* __restrict__ vin,
                            const float* __restrict__ Wq, const float* __restrict__ Wk,
                            const float* __restrict__ bk, const float* __restrict__ Wv,
                            const float* __restrict__ bv, const float* __restrict__ Wo,
                            float* __restrict__ ws) {
    const int gid = blockIdx.x * 256 + threadIdx.x;
    float* WqT = ws;
    float* WoT = ws + 4096;
    float* khs = ws + 8192;
    float* vh  = ws + 8704;
    double* zg = (double*)(ws + 9216);
    for (int idx = gid; idx < 4096; idx += 8 * 256) {
        int a = idx >> 6, b = idx & 63;
        WqT[idx] = Wq[b * 64 + a];
        WoT[idx] = Wo[b * 64 + a];
    }
    for (int idx = gid; idx < 512; idx += 8 * 256) {
        int b = idx >> 6, c = idx & 63;
        float dk = 0.f, dv = 0.f;
        #pragma unroll 8
        for (int j = 0; j < 64; ++j) {
            dk = fmaf(kin[b * 64 + j], Wk[c * 64 + j], dk);
            dv = fmaf(vin[b * 64 + j], Wv[c * 64 + j], dv);
        }
        khs[idx] = (dk + bk[c]) * SCALE;
        vh[idx]  = dv + bv[c];
        zg[idx]  = 0.0;
    }
}

// Thread mapping (both passes): cc = tid&7 -> channel quads {4cc..4cc+3, 32+4cc..32+4cc+3},
// ty = tid>>3 (0..31) -> points 4ty..4ty+3.  acc[4][8], 32 FMAs per LDS-read triple.

// passA: e = exp((q@Wq.T + bq) * khs[batch]) -> e_out (aliases d_out), z-accum (f64 global)
__global__ __launch_bounds__(256, 3) void passA_kernel(const float* __restrict__ q,
                                                       const int* __restrict__ batch,
                                                       const float* __restrict__ bq,
                                                       float* __restrict__ ws,
                                                       float* __restrict__ e_out) {
    __shared__ __align__(16) float qT[QT_SZ];
    __shared__ __align__(16) float wq[4096];
    __shared__ __align__(16) float khs_l[512];
    __shared__ __align__(16) float zred[256];

    const float* WqT   = ws;
    const float* khs_g = ws + 8192;
    double* zg = (double*)(ws + 9216);

    const int tid  = threadIdx.x;
    const int wid  = tid >> 6;
    const int lane = tid & 63;
    const int cc   = tid & 7;     // channel quads 4cc, 32+4cc
    const int ty   = tid >> 3;    // points 4ty..4ty+3 (0..31)

    for (int idx = tid; idx < 1024; idx += 256) ((float4*)wq)[idx] = ((const float4*)WqT)[idx];
    for (int idx = tid; idx < 128; idx += 256) ((float4*)khs_l)[idx] = ((const float4*)khs_g)[idx];

    float bqlo[4], bqhi[4];
    { float4 b4 = ((const float4*)bq)[cc];
      bqlo[0] = b4.x; bqlo[1] = b4.y; bqlo[2] = b4.z; bqlo[3] = b4.w;
      b4 = ((const float4*)bq)[8 + cc];
      bqhi[0] = b4.x; bqhi[1] = b4.y; bqhi[2] = b4.z; bqhi[3] = b4.w; }

    float zacc[8] = {};
    int cur_b = -1;

    // block-uniform call sites only
    auto flushz = [&](int b) {
        if (b < 0) return;
        #pragma unroll
        for (int j = 0; j < 8; ++j) {
            zacc[j] += __shfl_xor(zacc[j], 8);
            zacc[j] += __shfl_xor(zacc[j], 16);
            zacc[j] += __shfl_xor(zacc[j], 32);
        }
        __syncthreads();                 // zred reuse guard
        if ((lane >> 3) == 0) {
            *(float4*)&zred[wid * 64 + 4 * cc]      = make_float4(zacc[0], zacc[1], zacc[2], zacc[3]);
            *(float4*)&zred[wid * 64 + 32 + 4 * cc] = make_float4(zacc[4], zacc[5], zacc[6], zacc[7]);
        }
        __syncthreads();
        if (tid < 64) {
            float s = zred[tid] + zred[64 + tid] + zred[128 + tid] + zred[192 + tid];
            unsafeAtomicAdd(&zg[b * 64 + tid], (double)s);
        }
        #pragma unroll
        for (int j = 0; j < 8; ++j) zacc[j] = 0.f;
    };

    const int t0 = blockIdx.x * TPB;
    const int t1 = (t0 + TPB < NT128) ? (t0 + TPB) : NT128;
    __syncthreads();

    for (int t = t0; t < t1; ++t) {
        const int p0g = t * 128;

        // stage q tile, transposed (8 float4 global loads -> 32 scalar LDS writes)
        #pragma unroll
        for (int i = 0; i < 8; ++i) {
            const int g4 = t * 2048 + i * 256 + tid;
            float4 v = make_float4(0.f, 0.f, 0.f, 0.f);
            if (g4 < Q4TOT) v = ((const float4*)q)[g4];
            const int pl = i * 16 + (tid >> 4);   // 0..127
            const int kc = tid & 15;
            qT[QTIDX(4 * kc + 0, pl)] = v.x;
            qT[QTIDX(4 * kc + 1, pl)] = v.y;
            qT[QTIDX(4 * kc + 2, pl)] = v.z;
            qT[QTIDX(4 * kc + 3, pl)] = v.w;
        }
        const int b_lo = batch[p0g];
        const int b_hi = batch[(p0g + 127 < NPTS) ? (p0g + 127) : (NPTS - 1)];
        const bool uni = (b_lo == b_hi);
        __syncthreads();

        if (uni) {
            if (cur_b != b_lo) { flushz(cur_b); cur_b = b_lo; }
        } else {
            flushz(cur_b);
            cur_b = -1;
        }

        // GEMM1: qp[p][c] = sum_k q[p][k] * Wq[c][k]
        float acc[4][8] = {};
        #pragma unroll 4
        for (int kc = 0; kc < 16; ++kc) {
            #pragma unroll
            for (int j = 0; j < 4; ++j) {
                const float4 a4  = *(const float4*)&qT[kc * 532 + j * 132 + 4 * ty];
                const float4 wlo = *(const float4*)&wq[(kc * 4 + j) * 64 + 4 * cc];
                const float4 whi = *(const float4*)&wq[(kc * 4 + j) * 64 + 32 + 4 * cc];
                const float av[4] = {a4.x, a4.y, a4.z, a4.w};
                const float wl[4] = {wlo.x, wlo.y, wlo.z, wlo.w};
                const float wh[4] = {whi.x, whi.y, whi.z, whi.w};
                #pragma unroll
                for (int i = 0; i < 4; ++i) {
                    #pragma unroll
                    for (int m = 0; m < 4; ++m) {
                        acc[i][m]     = fmaf(av[i], wl[m], acc[i][m]);
                        acc[i][4 + m] = fmaf(av[i], wh[m], acc[i][4 + m]);
                    }
                }
            }
        }

        if (uni) {
            const float4 klo = *(const float4*)&khs_l[b_lo * 64 + 4 * cc];
            const float4 khi = *(const float4*)&khs_l[b_lo * 64 + 32 + 4 * cc];
            const float kl[4] = {klo.x, klo.y, klo.z, klo.w};
            const float kh[4] = {khi.x, khi.y, khi.z, khi.w};
            #pragma unroll
            for (int i = 0; i < 4; ++i) {
                const int gp = p0g + 4 * ty + i;
                if (gp < NPTS) {
                    float e0[4], e1[4];
                    #pragma unroll
                    for (int m = 0; m < 4; ++m) {
                        e0[m] = __expf((acc[i][m] + bqlo[m]) * kl[m]);
                        e1[m] = __expf((acc[i][4 + m] + bqhi[m]) * kh[m]);
                    }
                    ((float4*)e_out)[gp * 16 + cc]     = make_float4(e0[0], e0[1], e0[2], e0[3]);
                    ((float4*)e_out)[gp * 16 + 8 + cc] = make_float4(e1[0], e1[1], e1[2], e1[3]);
                    #pragma unroll
                    for (int m = 0; m < 4; ++m) { zacc[m] += e0[m]; zacc[4 + m] += e1[m]; }
                }
            }
        } else {
            // rare boundary tile (<=7 in the whole grid)
            #pragma unroll
            for (int i = 0; i < 4; ++i) {
                const int gp = p0g + 4 * ty + i;
                if (gp < NPTS) {
                    const int bi = batch[gp];
                    const float4 klo = *(const float4*)&khs_l[bi * 64 + 4 * cc];
                    const float4 khi = *(const float4*)&khs_l[bi * 64 + 32 + 4 * cc];
                    const float kl[4] = {klo.x, klo.y, klo.z, klo.w};
                    const float kh[4] = {khi.x, khi.y, khi.z, khi.w};
                    float e0[4], e1[4];
                    #pragma unroll
                    for (int m = 0; m < 4; ++m) {
                        e0[m] = __expf((acc[i][m] + bqlo[m]) * kl[m]);
                        e1[m] = __expf((acc[i][4 + m] + bqhi[m]) * kh[m]);
                    }
                    ((float4*)e_out)[gp * 16 + cc]     = make_float4(e0[0], e0[1], e0[2], e0[3]);
                    ((float4*)e_out)[gp * 16 + 8 + cc] = make_float4(e1[0], e1[1], e1[2], e1[3]);
                    #pragma unroll
                    for (int m = 0; m < 4; ++m) {
                        unsafeAtomicAdd(&zg[bi * 64 + 4 * cc + m], (double)e0[m]);
                        unsafeAtomicAdd(&zg[bi * 64 + 32 + 4 * cc + m], (double)e1[m]);
                    }
                }
            }
        }
        __syncthreads();   // qT about to be restaged
    }
    flushz(cur_b);
}

// passB: out = (e * (vh/z)[batch]) @ Wo.T + bo ; e read from d_out, written in place
__global__ __launch_bounds__(256, 3) void passB_kernel(const int* __restrict__ batch,
                                                       const float* __restrict__ bo,
                                                       const float* __restrict__ ws,
                                                       float* __restrict__ out) {
    __shared__ __align__(16) float tT[QT_SZ];
    __shared__ __align__(16) float wo[4096];
    __shared__ __align__(16) float w_l[512];

    const float* WoT  = ws + 4096;
    const float* vh_g = ws + 8704;
    const double* zg  = (const double*)(ws + 9216);

    const int tid = threadIdx.x;
    const int cc  = tid & 7;
    const int ty  = tid >> 3;

    for (int idx = tid; idx < 1024; idx += 256) ((float4*)wo)[idx] = ((const float4*)WoT)[idx];
    for (int idx = tid; idx < 512; idx += 256)
        w_l[idx] = (float)((double)vh_g[idx] / zg[idx]);

    float bolo[4], bohi[4];
    { float4 b4 = ((const float4*)bo)[cc];
      bolo[0] = b4.x; bolo[1] = b4.y; bolo[2] = b4.z; bolo[3] = b4.w;
      b4 = ((const float4*)bo)[8 + cc];
      bohi[0] = b4.x; bohi[1] = b4.y; bohi[2] = b4.z; bohi[3] = b4.w; }

    const int t0 = blockIdx.x * TPB;
    const int t1 = (t0 + TPB < NT128) ? (t0 + TPB) : NT128;
    __syncthreads();   // w_l ready

    for (int t = t0; t < t1; ++t) {
        const int p0g = t * 128;
        const int b_lo = batch[p0g];
        const int b_hi = batch[(p0g + 127 < NPTS) ? (p0g + 127) : (NPTS - 1)];
        const bool uni = (b_lo == b_hi);

        // stage t = e * w[batch], transposed, fold applied at stage time
        #pragma unroll
        for (int i = 0; i < 8; ++i) {
            const int g4 = t * 2048 + i * 256 + tid;
            float4 v = make_float4(0.f, 0.f, 0.f, 0.f);
            if (g4 < Q4TOT) v = ((const float4*)out)[g4];
            const int pl = i * 16 + (tid >> 4);   // 0..127
            const int kc = tid & 15;
            int bi = b_lo;
            if (!uni) {
                const int gp = p0g + pl;
                bi = batch[(gp < NPTS) ? gp : (NPTS - 1)];
            }
            const float4 wv = *(const float4*)&w_l[bi * 64 + 4 * kc];
            tT[QTIDX(4 * kc + 0, pl)] = v.x * wv.x;
            tT[QTIDX(4 * kc + 1, pl)] = v.y * wv.y;
            tT[QTIDX(4 * kc + 2, pl)] = v.z * wv.z;
            tT[QTIDX(4 * kc + 3, pl)] = v.w * wv.w;
        }
        __syncthreads();

        // GEMM2: out[p][c'] = sum_c t[p][c] * Wo[c'][c] + bo
        float acc[4][8] = {};
        #pragma unroll 4
        for (int kc = 0; kc < 16; ++kc) {
            #pragma unroll
            for (int j = 0; j < 4; ++j) {
                const float4 a4  = *(const float4*)&tT[kc * 532 + j * 132 + 4 * ty];
                const float4 wlo = *(const float4*)&wo[(kc * 4 + j) * 64 + 4 * cc];
                const float4 whi = *(const float4*)&wo[(kc * 4 + j) * 64 + 32 + 4 * cc];
                const float av[4] = {a4.x, a4.y, a4.z, a4.w};
                const float wl[4] = {wlo.x, wlo.y, wlo.z, wlo.w};
                const float wh[4] = {whi.x, whi.y, whi.z, whi.w};
                #pragma unroll
                for (int i = 0; i < 4; ++i) {
                    #pragma unroll
                    for (int m = 0; m < 4; ++m) {
                        acc[i][m]     = fmaf(av[i], wl[m], acc[i][m]);
                        acc[i][4 + m] = fmaf(av[i], wh[m], acc[i][4 + m]);
                    }
                }
            }
        }

        #pragma unroll
        for (int i = 0; i < 4; ++i) {
            const int gp = p0g + 4 * ty + i;
            if (gp < NPTS) {
                ((float4*)out)[gp * 16 + cc] =
                    make_float4(acc[i][0] + bolo[0], acc[i][1] + bolo[1],
                                acc[i][2] + bolo[2], acc[i][3] + bolo[3]);
                ((float4*)out)[gp * 16 + 8 + cc] =
                    make_float4(acc[i][4] + bohi[0], acc[i][5] + bohi[1],
                                acc[i][6] + bohi[2], acc[i][7] + bohi[3]);
            }
        }
        __syncthreads();   // tT about to be restaged
    }
}

extern "C" void kernel_launch(void* const* d_in, const int* in_sizes, int n_in,
                              void* d_out, int out_size, void* d_ws, size_t ws_size,
                              hipStream_t stream) {
    const float* q   = (const float*)d_in[0];
    const float* k   = (const float*)d_in[1];
    const float* v   = (const float*)d_in[2];
    const float* Wq  = (const float*)d_in[3];
    const float* bq  = (const float*)d_in[4];
    const float* Wk  = (const float*)d_in[5];
    const float* bk  = (const float*)d_in[6];
    const float* Wv  = (const float*)d_in[7];
    const float* bv  = (const float*)d_in[8];
    const float* Wo  = (const float*)d_in[9];
    const float* bo  = (const float*)d_in[10];
    const int*  batch = (const int*)d_in[11];
    float* out = (float*)d_out;
    float* ws  = (float*)d_ws;

    prep_kernel<<<8, 256, 0, stream>>>(k, v, Wq, Wk, bk, Wv, bv, Wo, ws);
    passA_kernel<<<GRID, 256, 0, stream>>>(q, batch, bq, ws, out);
    passB_kernel<<<GRID, 256, 0, stream>>>(batch, bo, ws, out);
}

// Round 5
// 339.242 us; speedup vs baseline: 18.5085x; 1.0304x over previous
//
#include <hip/hip_runtime.h>
#include <math.h>

// Problem constants (fixed by the reference)
#define NPTS 500000
#define SCALE 0.35355339059327373f   // 1/sqrt(8)
#define NT128 3907                   // ceil(500000/128)
#define TPB 2                        // 128-pt tiles per block
#define GRID ((NT128 + TPB - 1) / TPB)
#define Q4TOT 8000000                // NPTS*16 float4's in q / e / out

// Transposed 128-pt tile layout: element (k,p) lives at
//   (k>>2)*532 + (k&3)*132 + p
// Group stride 532 == 20 (mod 32): staging scalar writes cover all 32 banks 2-way
// (free, m136). Rows are 132 floats (528 B, 16B-aligned) so float4 reads at p=4*ty
// are aligned and spread across bank quads.
#define QTIDX(k, p) ((((k) >> 2) * 532) + (((k) & 3) * 132) + (p))
#define QT_SZ 8512

// ws layout (float offsets):
// [0,4096)      WqT[k][c] = Wq[c][k]
// [4096,8192)   WoT[c][c'] = Wo[c'][c]
// [8192,8704)   khs[b][c] = (k@Wk.T + bk)*scale
// [8704,9216)   vh[b][c]  = v@Wv.T + bv
// [9216,10240)  z as double[512]

__global__ void prep_kernel(const float* __restrict__ kin, const float* __restrict__ vin,
                            const float* __restrict__ Wq, const float* __restrict__ Wk,
                            const float* __restrict__ bk, const float* __restrict__ Wv,
                            const float* __restrict__ bv, const float* __restrict__ Wo,
                            float* __restrict__ ws) {
    const int gid = blockIdx.x * 256 + threadIdx.x;
    float* WqT = ws;
    float* WoT = ws + 4096;
    float* khs = ws + 8192;
    float* vh  = ws + 8704;
    double* zg = (double*)(ws + 9216);
    for (int idx = gid; idx < 4096; idx += 8 * 256) {
        int a = idx >> 6, b = idx & 63;
        WqT[idx] = Wq[b * 64 + a];
        WoT[idx] = Wo[b * 64 + a];
    }
    for (int idx = gid; idx < 512; idx += 8 * 256) {
        int b = idx >> 6, c = idx & 63;
        float dk = 0.f, dv = 0.f;
        #pragma unroll 8
        for (int j = 0; j < 64; ++j) {
            dk = fmaf(kin[b * 64 + j], Wk[c * 64 + j], dk);
            dv = fmaf(vin[b * 64 + j], Wv[c * 64 + j], dv);
        }
        khs[idx] = (dk + bk[c]) * SCALE;
        vh[idx]  = dv + bv[c];
        zg[idx]  = 0.0;
    }
}

// Prefetch tile T's global data into registers (T14 async-stage: issue early,
// consume at the next write phase — HBM latency hides under the current GEMM).
#define STAGE_LOAD(SRC, T) do { \
    const int base4_ = (T) * 2048; \
    _Pragma("unroll") \
    for (int i_ = 0; i_ < 8; ++i_) { \
        const int g4_ = base4_ + i_ * 256 + tid; \
        pf[i_] = make_float4(0.f, 0.f, 0.f, 0.f); \
        if (g4_ < Q4TOT) pf[i_] = ((const float4*)(SRC))[g4_]; \
    } \
    const int pA_ = (T) * 128; \
    pb_lo = batch[pA_]; \
    pb_hi = batch[(pA_ + 127 < NPTS) ? (pA_ + 127) : (NPTS - 1)]; \
} while (0)

// Thread mapping (both passes): cc = tid&7 -> channel quads {4cc..4cc+3, 32+4cc..32+4cc+3},
// ty = tid>>3 (0..31) -> points 4ty..4ty+3.  acc[4][8], 32 FMAs per LDS-read triple.

// passA: e = exp((q@Wq.T + bq) * khs[batch]) -> e_out (aliases d_out), z-accum (f64 global)
__global__ __launch_bounds__(256, 3) void passA_kernel(const float* __restrict__ q,
                                                       const int* __restrict__ batch,
                                                       const float* __restrict__ bq,
                                                       float* __restrict__ ws,
                                                       float* __restrict__ e_out) {
    __shared__ __align__(16) float qT[QT_SZ];
    __shared__ __align__(16) float wq[4096];
    __shared__ __align__(16) float khs_l[512];
    __shared__ __align__(16) float zred[256];

    const float* WqT   = ws;
    const float* khs_g = ws + 8192;
    double* zg = (double*)(ws + 9216);

    const int tid  = threadIdx.x;
    const int wid  = tid >> 6;
    const int lane = tid & 63;
    const int cc   = tid & 7;     // channel quads 4cc, 32+4cc
    const int ty   = tid >> 3;    // points 4ty..4ty+3 (0..31)

    for (int idx = tid; idx < 1024; idx += 256) ((float4*)wq)[idx] = ((const float4*)WqT)[idx];
    for (int idx = tid; idx < 128; idx += 256) ((float4*)khs_l)[idx] = ((const float4*)khs_g)[idx];

    float bqlo[4], bqhi[4];
    { float4 b4 = ((const float4*)bq)[cc];
      bqlo[0] = b4.x; bqlo[1] = b4.y; bqlo[2] = b4.z; bqlo[3] = b4.w;
      b4 = ((const float4*)bq)[8 + cc];
      bqhi[0] = b4.x; bqhi[1] = b4.y; bqhi[2] = b4.z; bqhi[3] = b4.w; }

    float zacc[8] = {};
    int cur_b = -1;

    // block-uniform call sites only
    auto flushz = [&](int b) {
        if (b < 0) return;
        #pragma unroll
        for (int j = 0; j < 8; ++j) {
            zacc[j] += __shfl_xor(zacc[j], 8);
            zacc[j] += __shfl_xor(zacc[j], 16);
            zacc[j] += __shfl_xor(zacc[j], 32);
        }
        __syncthreads();                 // zred reuse guard
        if ((lane >> 3) == 0) {
            *(float4*)&zred[wid * 64 + 4 * cc]      = make_float4(zacc[0], zacc[1], zacc[2], zacc[3]);
            *(float4*)&zred[wid * 64 + 32 + 4 * cc] = make_float4(zacc[4], zacc[5], zacc[6], zacc[7]);
        }
        __syncthreads();
        if (tid < 64) {
            float s = zred[tid] + zred[64 + tid] + zred[128 + tid] + zred[192 + tid];
            unsafeAtomicAdd(&zg[b * 64 + tid], (double)s);
        }
        #pragma unroll
        for (int j = 0; j < 8; ++j) zacc[j] = 0.f;
    };

    const int t0 = blockIdx.x * TPB;
    const int t1 = (t0 + TPB < NT128) ? (t0 + TPB) : NT128;

    float4 pf[8];
    int pb_lo, pb_hi;
    STAGE_LOAD(q, t0);               // prologue prefetch (latency exposed once)
    __syncthreads();                 // wq/khs_l ready

    for (int t = t0; t < t1; ++t) {
        const int p0g = t * 128;

        // write phase: staged regs -> transposed LDS tile (vmcnt wait lands here)
        #pragma unroll
        for (int i = 0; i < 8; ++i) {
            const int pl = i * 16 + (tid >> 4);   // 0..127
            const int kc = tid & 15;
            qT[QTIDX(4 * kc + 0, pl)] = pf[i].x;
            qT[QTIDX(4 * kc + 1, pl)] = pf[i].y;
            qT[QTIDX(4 * kc + 2, pl)] = pf[i].z;
            qT[QTIDX(4 * kc + 3, pl)] = pf[i].w;
        }
        const int b_lo = pb_lo;
        const int b_hi = pb_hi;
        const bool uni = (b_lo == b_hi);
        __syncthreads();             // bar A: tile ready

        if (uni) {
            if (cur_b != b_lo) { flushz(cur_b); cur_b = b_lo; }
        } else {
            flushz(cur_b);
            cur_b = -1;
        }

        // issue next tile's global loads BEFORE the GEMM (hidden under compute)
        if (t + 1 < t1) STAGE_LOAD(q, t + 1);

        // GEMM1: qp[p][c] = sum_k q[p][k] * Wq[c][k]
        float acc[4][8] = {};
        #pragma unroll 4
        for (int kc = 0; kc < 16; ++kc) {
            #pragma unroll
            for (int j = 0; j < 4; ++j) {
                const float4 a4  = *(const float4*)&qT[kc * 532 + j * 132 + 4 * ty];
                const float4 wlo = *(const float4*)&wq[(kc * 4 + j) * 64 + 4 * cc];
                const float4 whi = *(const float4*)&wq[(kc * 4 + j) * 64 + 32 + 4 * cc];
                const float av[4] = {a4.x, a4.y, a4.z, a4.w};
                const float wl[4] = {wlo.x, wlo.y, wlo.z, wlo.w};
                const float wh[4] = {whi.x, whi.y, whi.z, whi.w};
                #pragma unroll
                for (int i = 0; i < 4; ++i) {
                    #pragma unroll
                    for (int m = 0; m < 4; ++m) {
                        acc[i][m]     = fmaf(av[i], wl[m], acc[i][m]);
                        acc[i][4 + m] = fmaf(av[i], wh[m], acc[i][4 + m]);
                    }
                }
            }
        }

        if (uni) {
            const float4 klo = *(const float4*)&khs_l[b_lo * 64 + 4 * cc];
            const float4 khi = *(const float4*)&khs_l[b_lo * 64 + 32 + 4 * cc];
            const float kl[4] = {klo.x, klo.y, klo.z, klo.w};
            const float kh[4] = {khi.x, khi.y, khi.z, khi.w};
            #pragma unroll
            for (int i = 0; i < 4; ++i) {
                const int gp = p0g + 4 * ty + i;
                if (gp < NPTS) {
                    float e0[4], e1[4];
                    #pragma unroll
                    for (int m = 0; m < 4; ++m) {
                        e0[m] = __expf((acc[i][m] + bqlo[m]) * kl[m]);
                        e1[m] = __expf((acc[i][4 + m] + bqhi[m]) * kh[m]);
                    }
                    ((float4*)e_out)[gp * 16 + cc]     = make_float4(e0[0], e0[1], e0[2], e0[3]);
                    ((float4*)e_out)[gp * 16 + 8 + cc] = make_float4(e1[0], e1[1], e1[2], e1[3]);
                    #pragma unroll
                    for (int m = 0; m < 4; ++m) { zacc[m] += e0[m]; zacc[4 + m] += e1[m]; }
                }
            }
        } else {
            // rare boundary tile (<=7 in the whole grid)
            #pragma unroll
            for (int i = 0; i < 4; ++i) {
                const int gp = p0g + 4 * ty + i;
                if (gp < NPTS) {
                    const int bi = batch[gp];
                    const float4 klo = *(const float4*)&khs_l[bi * 64 + 4 * cc];
                    const float4 khi = *(const float4*)&khs_l[bi * 64 + 32 + 4 * cc];
                    const float kl[4] = {klo.x, klo.y, klo.z, klo.w};
                    const float kh[4] = {khi.x, khi.y, khi.z, khi.w};
                    float e0[4], e1[4];
                    #pragma unroll
                    for (int m = 0; m < 4; ++m) {
                        e0[m] = __expf((acc[i][m] + bqlo[m]) * kl[m]);
                        e1[m] = __expf((acc[i][4 + m] + bqhi[m]) * kh[m]);
                    }
                    ((float4*)e_out)[gp * 16 + cc]     = make_float4(e0[0], e0[1], e0[2], e0[3]);
                    ((float4*)e_out)[gp * 16 + 8 + cc] = make_float4(e1[0], e1[1], e1[2], e1[3]);
                    #pragma unroll
                    for (int m = 0; m < 4; ++m) {
                        unsafeAtomicAdd(&zg[bi * 64 + 4 * cc + m], (double)e0[m]);
                        unsafeAtomicAdd(&zg[bi * 64 + 32 + 4 * cc + m], (double)e1[m]);
                    }
                }
            }
        }
        __syncthreads();   // bar B: all reads of qT done; next write phase may begin
    }
    flushz(cur_b);
}

// passB: out = (e * (vh/z)[batch]) @ Wo.T + bo ; e read from d_out, written in place
__global__ __launch_bounds__(256, 3) void passB_kernel(const int* __restrict__ batch,
                                                       const float* __restrict__ bo,
                                                       const float* __restrict__ ws,
                                                       float* __restrict__ out) {
    __shared__ __align__(16) float tT[QT_SZ];
    __shared__ __align__(16) float wo[4096];
    __shared__ __align__(16) float w_l[512];

    const float* WoT  = ws + 4096;
    const float* vh_g = ws + 8704;
    const double* zg  = (const double*)(ws + 9216);

    const int tid = threadIdx.x;
    const int cc  = tid & 7;
    const int ty  = tid >> 3;

    for (int idx = tid; idx < 1024; idx += 256) ((float4*)wo)[idx] = ((const float4*)WoT)[idx];
    for (int idx = tid; idx < 512; idx += 256)
        w_l[idx] = (float)((double)vh_g[idx] / zg[idx]);

    float bolo[4], bohi[4];
    { float4 b4 = ((const float4*)bo)[cc];
      bolo[0] = b4.x; bolo[1] = b4.y; bolo[2] = b4.z; bolo[3] = b4.w;
      b4 = ((const float4*)bo)[8 + cc];
      bohi[0] = b4.x; bohi[1] = b4.y; bohi[2] = b4.z; bohi[3] = b4.w; }

    const int t0 = blockIdx.x * TPB;
    const int t1 = (t0 + TPB < NT128) ? (t0 + TPB) : NT128;

    float4 pf[8];
    int pb_lo, pb_hi;
    STAGE_LOAD(out, t0);             // prologue prefetch
    __syncthreads();                 // w_l ready

    for (int t = t0; t < t1; ++t) {
        const int p0g = t * 128;
        const int b_lo = pb_lo;
        const int b_hi = pb_hi;
        const bool uni = (b_lo == b_hi);

        // write phase: t = e * w[batch], transposed, fold applied at write time
        #pragma unroll
        for (int i = 0; i < 8; ++i) {
            const int pl = i * 16 + (tid >> 4);   // 0..127
            const int kc = tid & 15;
            int bi = b_lo;
            if (!uni) {
                const int gp = p0g + pl;
                bi = batch[(gp < NPTS) ? gp : (NPTS - 1)];
            }
            const float4 wv = *(const float4*)&w_l[bi * 64 + 4 * kc];
            tT[QTIDX(4 * kc + 0, pl)] = pf[i].x * wv.x;
            tT[QTIDX(4 * kc + 1, pl)] = pf[i].y * wv.y;
            tT[QTIDX(4 * kc + 2, pl)] = pf[i].z * wv.z;
            tT[QTIDX(4 * kc + 3, pl)] = pf[i].w * wv.w;
        }
        __syncthreads();             // bar A: tile ready

        // issue next tile's global loads BEFORE the GEMM (hidden under compute);
        // reads tile t+1 region, disjoint from this iteration's stores to tile t.
        if (t + 1 < t1) STAGE_LOAD(out, t + 1);

        // GEMM2: out[p][c'] = sum_c t[p][c] * Wo[c'][c] + bo
        float acc[4][8] = {};
        #pragma unroll 4
        for (int kc = 0; kc < 16; ++kc) {
            #pragma unroll
            for (int j = 0; j < 4; ++j) {
                const float4 a4  = *(const float4*)&tT[kc * 532 + j * 132 + 4 * ty];
                const float4 wlo = *(const float4*)&wo[(kc * 4 + j) * 64 + 4 * cc];
                const float4 whi = *(const float4*)&wo[(kc * 4 + j) * 64 + 32 + 4 * cc];
                const float av[4] = {a4.x, a4.y, a4.z, a4.w};
                const float wl[4] = {wlo.x, wlo.y, wlo.z, wlo.w};
                const float wh[4] = {whi.x, whi.y, whi.z, whi.w};
                #pragma unroll
                for (int i = 0; i < 4; ++i) {
                    #pragma unroll
                    for (int m = 0; m < 4; ++m) {
                        acc[i][m]     = fmaf(av[i], wl[m], acc[i][m]);
                        acc[i][4 + m] = fmaf(av[i], wh[m], acc[i][4 + m]);
                    }
                }
            }
        }

        #pragma unroll
        for (int i = 0; i < 4; ++i) {
            const int gp = p0g + 4 * ty + i;
            if (gp < NPTS) {
                ((float4*)out)[gp * 16 + cc] =
                    make_float4(acc[i][0] + bolo[0], acc[i][1] + bolo[1],
                                acc[i][2] + bolo[2], acc[i][3] + bolo[3]);
                ((float4*)out)[gp * 16 + 8 + cc] =
                    make_float4(acc[i][4] + bohi[0], acc[i][5] + bohi[1],
                                acc[i][6] + bohi[2], acc[i][7] + bohi[3]);
            }
        }
        __syncthreads();   // bar B: all reads of tT done; next write phase may begin
    }
}

extern "C" void kernel_launch(void* const* d_in, const int* in_sizes, int n_in,
                              void* d_out, int out_size, void* d_ws, size_t ws_size,
                              hipStream_t stream) {
    const float* q   = (const float*)d_in[0];
    const float* k   = (const float*)d_in[1];
    const float* v   = (const float*)d_in[2];
    const float* Wq  = (const float*)d_in[3];
    const float* bq  = (const float*)d_in[4];
    const float* Wk  = (const float*)d_in[5];
    const float* bk  = (const float*)d_in[6];
    const float* Wv  = (const float*)d_in[7];
    const float* bv  = (const float*)d_in[8];
    const float* Wo  = (const float*)d_in[9];
    const float* bo  = (const float*)d_in[10];
    const int*  batch = (const int*)d_in[11];
    float* out = (float*)d_out;
    float* ws  = (float*)d_ws;

    prep_kernel<<<8, 256, 0, stream>>>(k, v, Wq, Wk, bk, Wv, bv, Wo, ws);
    passA_kernel<<<GRID, 256, 0, stream>>>(q, batch, bq, ws, out);
    passB_kernel<<<GRID, 256, 0, stream>>>(batch, bo, ws, out);
}